// Round 12
// baseline (274.295 us; speedup 1.0000x reference)
//
#include <hip/hip_runtime.h>
#include <stdint.h>

#define N_NODES 207
#define N_EDGES 1722
#define N_SLOTS 288
#define L_DIM   64
#define CSRP_CAP 4096    // node-ordered padded CSR capacity (<= 4065)
#define WSTR_CAP 4608    // wave-ordered stream capacity (<= 4272 worst case)
#define W16_STRIDE 4608  // u16 per slot in w16 table
#define NGRP_CAP 1280    // group capacity (<= 1068) + sentinel

__device__ __forceinline__ unsigned int f2bf_rtn_bits_hi(float f) {
    unsigned int u = __float_as_uint(f);
    unsigned int r = u + 0x7FFFu + ((u >> 16) & 1u);
    return r & 0xFFFF0000u;
}
__device__ __forceinline__ float uf(unsigned int u) { return __uint_as_float(u); }

// ---------------------------------------------------------------------------
// K1: build node-ordered padded CSR (csr_p/rs_p, for K1b deg + fallback) AND
// the wave-ordered flat stream: node n -> wave n&7; each node's 4-padded
// (min 4) segment is contiguous in its wave's region. Emits:
//   csr_w[k]  = (edge_id<<8)|nb (pads 0xFFFFFFFF), wave-ordered
//   topo8[k]  = nb byte (pads 0)
//   nodearr[g]= node id of group g (u8), sentinel 0xFF after last group
//   wvoff[w]  = entry offset of wave w's region (w=0..8)
// ---------------------------------------------------------------------------
__global__ __launch_bounds__(256) void build_csr_kernel(
    const int* __restrict__ edge_i, const int* __restrict__ edge_j,
    int* __restrict__ rs_p, unsigned int* __restrict__ csr_p,
    unsigned int* __restrict__ csr_w, unsigned char* __restrict__ topo8,
    unsigned char* __restrict__ nodearr, int* __restrict__ wvoff) {
    __shared__ int cnt[N_NODES];
    __shared__ int rs[N_NODES + 1];
    __shared__ int nbase[N_NODES];
    __shared__ int ngsz[N_NODES];
    const int tid = threadIdx.x;

    for (int n = tid; n < N_NODES; n += 256) cnt[n] = 0;
    __syncthreads();
    for (int e = tid; e < N_EDGES; e += 256) {
        atomicAdd(&cnt[edge_i[e]], 1);
        atomicAdd(&cnt[edge_j[e]], 1);
    }
    __syncthreads();
    if (tid == 0) {
        int acc = 0;
        for (int n = 0; n < N_NODES; ++n) { rs[n] = acc; acc += (cnt[n] + 3) & ~3; }
        rs[N_NODES] = acc;   // <= 4065
    }
    __syncthreads();
    for (int n = tid; n <= N_NODES; n += 256) rs_p[n] = rs[n];
    for (int k = tid; k < CSRP_CAP; k += 256) csr_p[k] = 0xFFFFFFFFu;
    for (int n = tid; n < N_NODES; n += 256) cnt[n] = rs[n];
    __syncthreads();
    for (int e = tid; e < N_EDGES; e += 256) {
        const unsigned int i = edge_i[e], j = edge_j[e];
        const unsigned int ep = ((unsigned int)e) << 8;
        int p = atomicAdd(&cnt[i], 1);
        csr_p[p] = ep | j;
        int q = atomicAdd(&cnt[j], 1);
        csr_p[q] = ep | i;
    }
    __syncthreads();
    // wave-ordered layout (serial, tiny)
    if (tid == 0) {
        int wsz[8] = {0,0,0,0,0,0,0,0};
        for (int n = 0; n < N_NODES; ++n) {
            int dp = rs[n + 1] - rs[n];
            int g = (dp > 4) ? dp : 4;            // min one group per node
            ngsz[n] = g;
            wsz[n & 7] += g;
        }
        int acc = 0, wo[9];
        for (int w = 0; w < 8; ++w) { wo[w] = acc; acc += wsz[w]; }
        wo[8] = acc;                               // total entries (<= 4272)
        for (int w = 0; w <= 8; ++w) wvoff[w] = wo[w];
        int cur[8];
        for (int w = 0; w < 8; ++w) cur[w] = wo[w];
        for (int n = 0; n < N_NODES; ++n) {
            const int w = n & 7;
            nbase[n] = cur[w];
            cur[w] += ngsz[n];
        }
        nodearr[acc >> 2] = 0xFFu;                 // sentinel after last group
    }
    __syncthreads();
    for (int n = tid; n < N_NODES; n += 256) {
        const int b0 = nbase[n], dp = rs[n + 1] - rs[n], g = ngsz[n];
        for (int i = 0; i < dp; ++i) {
            const unsigned int c = csr_p[rs[n] + i];
            csr_w[b0 + i] = c;
            topo8[b0 + i] = (unsigned char)(c & 255u);
        }
        for (int i = dp; i < g; ++i) {
            csr_w[b0 + i] = 0xFFFFFFFFu;
            topo8[b0 + i] = 0;
        }
        const int G = g >> 2, gb = b0 >> 2;
        for (int j = 0; j < G; ++j) nodearr[gb + j] = (unsigned char)n;
    }
}

// ---------------------------------------------------------------------------
// K1b: per slot: coefbias {1+wsl+deg, bias}; bf16 weight stream w16[s][k] in
// WAVE order (pads -> 0), 9.2 KB/slot.
// ---------------------------------------------------------------------------
__global__ __launch_bounds__(256) void coef_eb_kernel(
    const float* __restrict__ weight_diff, const float* __restrict__ bias_diffusion,
    const float* __restrict__ weight_self_loop,
    const int* __restrict__ rs_p, const unsigned int* __restrict__ csr_p,
    const unsigned int* __restrict__ csr_w, const int* __restrict__ wvoff,
    float2* __restrict__ coefbias, unsigned short* __restrict__ w16) {
    __shared__ float wrow[N_EDGES];
    const int s = blockIdx.x;
    for (int e = threadIdx.x; e < N_EDGES; e += 256)
        wrow[e] = weight_diff[(size_t)s * N_EDGES + e];
    __syncthreads();

    if (w16 != nullptr) {
        const int total = wvoff[8];
        unsigned short* ws = w16 + (size_t)s * W16_STRIDE;
        for (int k = threadIdx.x; k < total; k += 256) {
            const unsigned int c = csr_w[k];
            ws[k] = (c == 0xFFFFFFFFu)
                  ? (unsigned short)0
                  : (unsigned short)(f2bf_rtn_bits_hi(wrow[c >> 8]) >> 16);
        }
    }

    const int n = threadIdx.x;
    if (n < N_NODES) {
        float d = 0.f;
        const int e0 = rs_p[n], e1 = rs_p[n + 1];
        for (int k = e0; k < e1; ++k) {
            const unsigned int c = csr_p[k];
            if (c != 0xFFFFFFFFu) d += wrow[c >> 8];
        }
        coefbias[s * N_NODES + n] = make_float2(
            1.f + weight_self_loop[s * N_NODES + n] + d,
            bias_diffusion[s * N_NODES + n]);
    }
}

// ---------------------------------------------------------------------------
// K2 (flat stream, all-LDS loop): one block (512 thr = 8 waves) per batch elem.
// r11 post-mortem: gather loop latency-bound; edge stream L2-evicted by x/out
// streaming -> L3 hits (~400-600cyc) serialized at node boundaries. Fix:
//  - ALL loop operands in LDS (w bf16 8.7KB + topo 4.3KB + group-node 1.2KB)
//  - flat per-wave group loop (no per-node nesting): chains pipeline across
//    node boundaries; flush on wave-uniform LDS compare node[g+1]!=node[g]
//  - x-gather ds_read_b64 (quad h = edge g*4+h, 16 lanes x l=4i..4i+3)
// LDS = 26,496 + 8,704 + 4,352 + 1,152 = 40,704 <= 40,960 -> 4 blocks/CU.
// ---------------------------------------------------------------------------
__global__ __launch_bounds__(512, 8) void diffusion_flat_kernel(
    const float* __restrict__ inputs,            // (B, 2, 207, 64)
    const int*   __restrict__ ind,               // (B,)
    const int*   __restrict__ wvoff,             // (9,)
    const unsigned char*  __restrict__ topo8,    // wave-ordered nb bytes
    const unsigned char*  __restrict__ nodearr,  // per-group node id + sentinel
    const unsigned short* __restrict__ w16,      // (288, W16_STRIDE) bf16 weights
    const float2* __restrict__ coefbias,         // (288, 207)
    float* __restrict__ out) {                   // (B, 207, 64)
    __shared__ unsigned short xs[N_NODES * L_DIM];   // 26,496 B
    __shared__ unsigned short ws16[WSTR_CAP - 256];  //  8,704 B (4352 entries)
    __shared__ unsigned char  tp[WSTR_CAP - 256];    //  4,352 B
    __shared__ unsigned char  ndl[1152];             //  1,152 B

    const int b    = blockIdx.x;
    const int tid  = threadIdx.x;
    const int slot = ind[b];
    const int total = wvoff[8];                  // uniform, one-time

    const float* xb = inputs + (size_t)b * (2 * N_NODES * L_DIM);  // channel 0

    // Stage x (fp32 global, float4) -> bf16 LDS
    const float4* xb4 = (const float4*)xb;
    for (int k = tid; k < (N_NODES * L_DIM) / 4; k += 512) {
        const float4 v = xb4[k];
        const unsigned int lo = (f2bf_rtn_bits_hi(v.x) >> 16) | f2bf_rtn_bits_hi(v.y);
        const unsigned int hi = (f2bf_rtn_bits_hi(v.z) >> 16) | f2bf_rtn_bits_hi(v.w);
        ((uint2*)xs)[k] = make_uint2(lo, hi);
    }
    // Stage weight stream (u32 copies), topology, group-node map
    {
        const unsigned int* wg = (const unsigned int*)(w16 + (size_t)slot * W16_STRIDE);
        for (int k = tid; k < (total >> 1); k += 512) ((unsigned int*)ws16)[k] = wg[k];
        const unsigned int* tg = (const unsigned int*)topo8;
        for (int k = tid; k < (total >> 2); k += 512) ((unsigned int*)tp)[k] = tg[k];
        const unsigned int* ng = (const unsigned int*)nodearr;
        const int ngw = ((total >> 2) + 1 + 3) >> 2;   // groups + sentinel, in u32
        for (int k = tid; k < ngw; k += 512) ((unsigned int*)ndl)[k] = ng[k];
    }
    __syncthreads();

    const int lane = tid & 63;
    const int wv   = tid >> 6;                   // 8 waves
    const int h    = lane >> 4;                  // quad 0..3 -> edge g*4+h
    const unsigned int li8 = (unsigned int)((lane & 15) << 3);
    const float2* cbs = coefbias + (size_t)slot * N_NODES;
    float* ob = out + (size_t)b * (N_NODES * L_DIM);
    const char* xsb = (const char*)xs;

    const int g0 = wvoff[wv] >> 2;
    const int g1 = wvoff[wv + 1] >> 2;
    float s0 = 0.f, s1 = 0.f, s2 = 0.f, s3 = 0.f;
    unsigned int nCur = ndl[g0];
    #pragma unroll 2
    for (int g = g0; g < g1; ++g) {
        const unsigned int nNext = ndl[g + 1];             // LDS u8 (sentinel-safe)
        const int e = (g << 2) + h;
        const unsigned int wbits = ((unsigned int)ws16[e]) << 16;
        const unsigned int off = ((unsigned int)tp[e] << 7) | li8;
        const uint2 xv = *(const uint2*)(xsb + off);       // ds_read_b64
        s0 = fmaf(uf(wbits), uf(xv.x << 16),         s0);
        s1 = fmaf(uf(wbits), uf(xv.x & 0xFFFF0000u), s1);
        s2 = fmaf(uf(wbits), uf(xv.y << 16),         s2);
        s3 = fmaf(uf(wbits), uf(xv.y & 0xFFFF0000u), s3);
        if (nNext != nCur) {                                // wave-uniform flush
            float r0 = s0, r1 = s1, r2 = s2, r3 = s3;
            r0 += __shfl_xor(r0, 16); r1 += __shfl_xor(r1, 16);
            r2 += __shfl_xor(r2, 16); r3 += __shfl_xor(r3, 16);
            r0 += __shfl_xor(r0, 32); r1 += __shfl_xor(r1, 32);
            r2 += __shfl_xor(r2, 32); r3 += __shfl_xor(r3, 32);
            if (lane < 16) {
                const int n = (int)nCur;
                const float2 cb = cbs[n];
                const int o4 = (n << 6) + (lane << 2);
                const float4 xg = *(const float4*)(xb + o4);
                float4 o;
                o.x = fmaf(cb.x, xg.x, cb.y) - r0;
                o.y = fmaf(cb.x, xg.y, cb.y) - r1;
                o.z = fmaf(cb.x, xg.z, cb.y) - r2;
                o.w = fmaf(cb.x, xg.w, cb.y) - r3;
                *(float4*)(ob + o4) = o;
            }
            s0 = s1 = s2 = s3 = 0.f;
            nCur = nNext;
        }
    }
}

// ---------------------------------------------------------------------------
// K2 (fallback, r8-verified pattern): per-block weight gather + u16 LDS reads.
// ---------------------------------------------------------------------------
__global__ __launch_bounds__(512, 4) void diffusion_gcn_fallback(
    const float* __restrict__ inputs,
    const float* __restrict__ weight_diff,
    const int*   __restrict__ ind,
    const int*   __restrict__ rs_p_g,
    const unsigned int* __restrict__ csr_p,
    const float2* __restrict__ coefbias,
    float* __restrict__ out) {
    __shared__ unsigned short xsh[N_NODES * L_DIM];
    __shared__ unsigned int   wnb[CSRP_CAP];
    __shared__ unsigned short rs[N_NODES + 1];

    const int b    = blockIdx.x;
    const int tid  = threadIdx.x;
    const int slot = ind[b];

    const float* xb = inputs + (size_t)b * (2 * N_NODES * L_DIM);

    const float4* xb4 = (const float4*)xb;
    for (int k = tid; k < (N_NODES * L_DIM) / 4; k += 512) {
        const float4 v = xb4[k];
        const unsigned int lo = (f2bf_rtn_bits_hi(v.x) >> 16) | f2bf_rtn_bits_hi(v.y);
        const unsigned int hi = (f2bf_rtn_bits_hi(v.z) >> 16) | f2bf_rtn_bits_hi(v.w);
        ((uint2*)xsh)[k] = make_uint2(lo, hi);
    }
    const int EP = rs_p_g[N_NODES];
    const float* wrow = weight_diff + (size_t)slot * N_EDGES;
    for (int k = tid; k < EP; k += 512) {
        const unsigned int c = csr_p[k];
        wnb[k] = (c == 0xFFFFFFFFu) ? 0u
                                    : (f2bf_rtn_bits_hi(wrow[c >> 8]) | (c & 255u));
    }
    for (int n = tid; n <= N_NODES; n += 512) rs[n] = (unsigned short)rs_p_g[n];
    __syncthreads();

    const int lane = tid & 63;
    const int wv   = tid >> 6;
    float* ob = out + (size_t)b * (N_NODES * L_DIM);

    for (int n = wv; n < N_NODES; n += 8) {
        const int e0 = rs[n], e1 = rs[n + 1];
        float s = 0.f;
        #pragma unroll 4
        for (int k = e0; k < e1; ++k) {
            const unsigned int p = wnb[k];
            const float w  = __uint_as_float(p & 0xFFFF0000u);
            const float xv = __uint_as_float(
                (unsigned int)xsh[(p & 255u) * L_DIM + lane] << 16);
            s = fmaf(w, xv, s);
        }
        const float2 cb = coefbias[slot * N_NODES + n];
        const float  xg = xb[n * L_DIM + lane];
        ob[n * L_DIM + lane] = fmaf(cb.x, xg, cb.y) - s;
    }
}

extern "C" void kernel_launch(void* const* d_in, const int* in_sizes, int n_in,
                              void* d_out, int out_size, void* d_ws, size_t ws_size,
                              hipStream_t stream) {
    const float* inputs           = (const float*)d_in[0];
    const float* weight_diff      = (const float*)d_in[1];
    const float* bias_diffusion   = (const float*)d_in[2];
    const float* weight_self_loop = (const float*)d_in[3];
    const int*   ind              = (const int*)d_in[4];
    const int*   edge_i           = (const int*)d_in[5];
    const int*   edge_j           = (const int*)d_in[6];
    float* out = (float*)d_out;

    const int B = in_sizes[4];                 // 1024

    // ws layout
    char* ws = (char*)d_ws;
    int*            rs_p     = (int*)ws;                          //      1,024 B
    unsigned int*   csr_p    = (unsigned int*)(ws + 1024);        //     16,384 B
    unsigned int*   csr_w    = (unsigned int*)(ws + 17408);       //     18,432 B
    unsigned char*  topo8    = (unsigned char*)(ws + 35840);      //      4,608 B
    unsigned char*  nodearr  = (unsigned char*)(ws + 40448);      //      1,280 B
    int*            wvoff    = (int*)(ws + 41728);                //         64 B
    float2*         coefbias = (float2*)(ws + 41792);             //    476,928 B
    unsigned short* w16      = (unsigned short*)(ws + 518720);    //  2,654,208 B
    const size_t WS_FULL = 518720 + (size_t)N_SLOTS * W16_STRIDE * sizeof(unsigned short);

    const bool full = (d_ws != nullptr) && (ws_size >= WS_FULL);

    build_csr_kernel<<<1, 256, 0, stream>>>(
        edge_i, edge_j, rs_p, csr_p, csr_w, topo8, nodearr, wvoff);
    coef_eb_kernel<<<N_SLOTS, 256, 0, stream>>>(
        weight_diff, bias_diffusion, weight_self_loop, rs_p, csr_p, csr_w, wvoff,
        coefbias, full ? w16 : nullptr);
    if (full) {
        diffusion_flat_kernel<<<B, 512, 0, stream>>>(
            inputs, ind, wvoff, topo8, nodearr, w16, coefbias, out);
    } else {
        diffusion_gcn_fallback<<<B, 512, 0, stream>>>(
            inputs, weight_diff, ind, rs_p, csr_p, coefbias, out);
    }
}

// Round 13
// 241.119 us; speedup vs baseline: 1.1376x; 1.1376x over previous
//
#include <hip/hip_runtime.h>
#include <stdint.h>

#define N_NODES 207
#define N_EDGES 1722
#define N_SLOTS 288
#define L_DIM   64
#define CSRP_CAP 4096      // 4-padded node CSR capacity (<= 4065)
#define T_CAP   256        // per-stream row capacity (measured need ~140)
#define T_ROWS  (T_CAP + 2)   // +2 prefetch pad rows
#define SLOT_U32 (32 * T_ROWS)  // u32 per slot in p32 table = 8256

__device__ __forceinline__ unsigned int f2bf_rtn_bits_hi(float f) {
    unsigned int u = __float_as_uint(f);
    unsigned int r = u + 0x7FFFu + ((u >> 16) & 1u);
    return r & 0xFFFF0000u;
}
__device__ __forceinline__ float uf(unsigned int u) { return __uint_as_float(u); }

// ---------------------------------------------------------------------------
// K1: build 4-padded CSR (for K1b deg + fallback) AND the 32-quad-stream
// meta table m32[t][q]:
//   node n -> stream q = n&31; quad q walks nodes q, q+32, ... in order.
//   entry = eid<<9 | nb<<1 | lastflag  (eid=2047 => pad, weight 0)
//   every node contributes max(deg,1) entries; last entry has flag=1.
// Streams padded to T (=max len) + 2 rows. stream_T[0] = T.
// ---------------------------------------------------------------------------
__global__ __launch_bounds__(256) void build_csr_kernel(
    const int* __restrict__ edge_i, const int* __restrict__ edge_j,
    int* __restrict__ rs_p, unsigned int* __restrict__ csr_p,
    unsigned int* __restrict__ m32, int* __restrict__ stream_T) {
    __shared__ int cnt[N_NODES];
    __shared__ int rs[N_NODES + 1];
    __shared__ int scnt[N_NODES];
    __shared__ int nsbase[N_NODES];
    __shared__ int slen[32];
    __shared__ int sT;
    const int tid = threadIdx.x;

    for (int n = tid; n < N_NODES; n += 256) cnt[n] = 0;
    __syncthreads();
    for (int e = tid; e < N_EDGES; e += 256) {
        atomicAdd(&cnt[edge_i[e]], 1);
        atomicAdd(&cnt[edge_j[e]], 1);
    }
    __syncthreads();
    if (tid == 0) {
        int acc = 0;
        for (int n = 0; n < N_NODES; ++n) { rs[n] = acc; acc += (cnt[n] + 3) & ~3; }
        rs[N_NODES] = acc;   // <= 4065
    }
    __syncthreads();
    for (int n = tid; n <= N_NODES; n += 256) rs_p[n] = rs[n];
    for (int k = tid; k < CSRP_CAP; k += 256) csr_p[k] = 0xFFFFFFFFu;  // pads
    for (int n = tid; n < N_NODES; n += 256) cnt[n] = rs[n];
    __syncthreads();
    for (int e = tid; e < N_EDGES; e += 256) {
        const unsigned int i = edge_i[e], j = edge_j[e];
        const unsigned int ep = ((unsigned int)e) << 8;
        int p = atomicAdd(&cnt[i], 1);
        csr_p[p] = ep | j;
        int q = atomicAdd(&cnt[j], 1);
        csr_p[q] = ep | i;
    }
    __syncthreads();
    for (int n = tid; n < N_NODES; n += 256) scnt[n] = cnt[n];
    __syncthreads();
    if (tid == 0) {
        int T = 0;
        for (int q = 0; q < 32; ++q) {
            int off = 0;
            for (int n = q; n < N_NODES; n += 32) {
                nsbase[n] = off;
                const int deg = scnt[n] - rs[n];
                off += (deg > 0) ? deg : 1;
            }
            slen[q] = off;
            if (off > T) T = off;
        }
        if (T > T_CAP) T = T_CAP;      // safety clamp (measured need ~140)
        sT = T;
        stream_T[0] = T;
    }
    __syncthreads();
    const int T2 = sT + 2;
    for (int n = tid; n < N_NODES; n += 256) {
        const int q = n & 31;
        const int deg = scnt[n] - rs[n];
        if (deg == 0) {
            if (nsbase[n] < T2) m32[nsbase[n] * 32 + q] = (2047u << 9) | 1u;
        } else {
            for (int i = 0; i < deg; ++i) {
                const int t = nsbase[n] + i;
                if (t >= T2) break;
                const unsigned int c = csr_p[rs[n] + i];
                const unsigned int fl = (i == deg - 1) ? 1u : 0u;
                m32[t * 32 + q] = ((c >> 8) << 9) | ((c & 255u) << 1) | fl;
            }
        }
    }
    for (int idx = tid; idx < 32 * T2; idx += 256) {
        const int t = idx >> 5, q = idx & 31;
        if (t >= slen[q]) m32[t * 32 + q] = (2047u << 9);   // pad: w->0, flag 0
    }
}

// ---------------------------------------------------------------------------
// K1b: per slot: coefbias {1+wsl+deg, bias}; packed stream p32[s][t][q] =
//   bf16(w)<<16 | nb<<7 | lastflag  (pads -> w 0)
// ---------------------------------------------------------------------------
__global__ __launch_bounds__(256) void coef_eb_kernel(
    const float* __restrict__ weight_diff, const float* __restrict__ bias_diffusion,
    const float* __restrict__ weight_self_loop,
    const int* __restrict__ rs_p, const unsigned int* __restrict__ csr_p,
    const unsigned int* __restrict__ m32, const int* __restrict__ stream_T,
    float2* __restrict__ coefbias, unsigned int* __restrict__ p32) {
    __shared__ float wrow[N_EDGES];
    const int s = blockIdx.x;
    for (int e = threadIdx.x; e < N_EDGES; e += 256)
        wrow[e] = weight_diff[(size_t)s * N_EDGES + e];
    __syncthreads();

    if (p32 != nullptr) {
        const int total = 32 * (stream_T[0] + 2);
        unsigned int* ps = p32 + (size_t)s * SLOT_U32;
        for (int k = threadIdx.x; k < total; k += 256) {
            const unsigned int m = m32[k];
            const unsigned int eid = m >> 9;
            const unsigned int nb  = (m >> 1) & 255u;
            const unsigned int fl  = m & 1u;
            const unsigned int w16 = (eid < N_EDGES) ? f2bf_rtn_bits_hi(wrow[eid]) : 0u;
            ps[k] = w16 | (nb << 7) | fl;
        }
    }

    const int n = threadIdx.x;
    if (n < N_NODES) {
        float d = 0.f;
        const int e0 = rs_p[n], e1 = rs_p[n + 1];
        for (int k = e0; k < e1; ++k) {
            const unsigned int c = csr_p[k];
            if (c != 0xFFFFFFFFu) d += wrow[c >> 8];
        }
        coefbias[s * N_NODES + n] = make_float2(
            1.f + weight_self_loop[s * N_NODES + n] + d,
            bias_diffusion[s * N_NODES + n]);
    }
}

// ---------------------------------------------------------------------------
// K2 (quad-autonomous stream): one block (512 thr = 8 waves) per batch elem.
// r12 decomposition: gather phase was LDS-PIPE bound (4 DS/group + shfl
// flushes ~57us/CU) or L3-latency bound (global-stream variants). This kernel:
//  - quad (16 lanes) covers full l-dim (16 x b64 = 64 l) -> ZERO shfl ever
//  - 1 ds_read_b64 per 4 edges = only in-loop DS op (~10us/CU total)
//  - stream from global [t][32] table, explicit 2-row register prefetch
//  - flush per-quad exec-masked; cb/xg prefetched at the PREVIOUS flush
//    (~17 iterations of latency hiding); exact 256B row writes
// LDS = 26,496 B -> 4 blocks/CU (wave cap).
// ---------------------------------------------------------------------------
__global__ __launch_bounds__(512, 8) void diffusion_stream_kernel(
    const float* __restrict__ inputs,          // (B, 2, 207, 64)
    const int*   __restrict__ ind,             // (B,)
    const int*   __restrict__ stream_T,        // (1,)
    const unsigned int* __restrict__ p32,      // (288, SLOT_U32)
    const float2* __restrict__ coefbias,       // (288, 207)
    float* __restrict__ out) {                 // (B, 207, 64)
    __shared__ unsigned short xs[N_NODES * L_DIM];   // 26,496 B (bf16, row 128 B)

    const int b    = blockIdx.x;
    const int tid  = threadIdx.x;
    const int slot = ind[b];
    const int T    = stream_T[0];              // uniform s_load, one-time

    const float* xb = inputs + (size_t)b * (2 * N_NODES * L_DIM);  // channel 0

    // Stage x (fp32 global, float4) -> bf16 LDS
    const float4* xb4 = (const float4*)xb;
    for (int k = tid; k < (N_NODES * L_DIM) / 4; k += 512) {
        const float4 v = xb4[k];
        const unsigned int lo = (f2bf_rtn_bits_hi(v.x) >> 16) | f2bf_rtn_bits_hi(v.y);
        const unsigned int hi = (f2bf_rtn_bits_hi(v.z) >> 16) | f2bf_rtn_bits_hi(v.w);
        ((uint2*)xs)[k] = make_uint2(lo, hi);
    }
    __syncthreads();

    const int lane = tid & 63;
    const int wv   = tid >> 6;
    const int q    = (wv << 2) | (lane >> 4);  // quad-stream id 0..31
    const int i4   = (lane & 15) << 2;         // l base (4 per lane)
    const unsigned int li8 = (unsigned int)((lane & 15) << 3);
    const unsigned int* ebs = p32 + (size_t)slot * SLOT_U32 + q;
    const float2* cbs = coefbias + (size_t)slot * N_NODES;
    float* ob = out + (size_t)b * (N_NODES * L_DIM);
    const char* xsb = (const char*)xs;

    int n = q;                                  // quad's current node
    float2 cb = cbs[n];                         // prefetched coef/bias
    float4 xg = *(const float4*)(xb + (n << 6) + i4);   // prefetched self term
    float s0 = 0.f, s1 = 0.f, s2 = 0.f, s3 = 0.f;
    unsigned int p0 = ebs[0];
    unsigned int p1 = ebs[32];
    for (int t = 0; t < T; ++t) {
        const unsigned int p2 = ebs[(t + 2) << 5];      // prefetch (in-bounds: +2 pad rows)
        const unsigned int p = p0;
        const uint2 xv = *(const uint2*)(xsb + ((p & 0x7F80u) | li8));  // ds_read_b64
        const unsigned int w = p & 0xFFFF0000u;
        s0 = fmaf(uf(w), uf(xv.x << 16),         s0);
        s1 = fmaf(uf(w), uf(xv.x & 0xFFFF0000u), s1);
        s2 = fmaf(uf(w), uf(xv.y << 16),         s2);
        s3 = fmaf(uf(w), uf(xv.y & 0xFFFF0000u), s3);
        if (p & 1u) {                          // per-quad flush (exec-masked)
            float4 o;
            o.x = fmaf(cb.x, xg.x, cb.y) - s0;
            o.y = fmaf(cb.x, xg.y, cb.y) - s1;
            o.z = fmaf(cb.x, xg.z, cb.y) - s2;
            o.w = fmaf(cb.x, xg.w, cb.y) - s3;
            *(float4*)(ob + (n << 6) + i4) = o;
            s0 = s1 = s2 = s3 = 0.f;
            n += 32;
            if (n < N_NODES) {                 // prefetch next node's cb/xg
                cb = cbs[n];
                xg = *(const float4*)(xb + (n << 6) + i4);
            }
        }
        p0 = p1; p1 = p2;
    }
}

// ---------------------------------------------------------------------------
// K2 (fallback, r8-verified pattern): per-block weight gather + u16 LDS reads.
// LDS = 26,496 + 16,384 + 416 = 43.3 KB -> 3 blocks/CU.
// ---------------------------------------------------------------------------
__global__ __launch_bounds__(512, 6) void diffusion_gcn_fallback(
    const float* __restrict__ inputs,
    const float* __restrict__ weight_diff,
    const int*   __restrict__ ind,
    const int*   __restrict__ rs_p_g,
    const unsigned int* __restrict__ csr_p,
    const float2* __restrict__ coefbias,
    float* __restrict__ out) {
    __shared__ unsigned short xsh[N_NODES * L_DIM];
    __shared__ unsigned int   wnb[CSRP_CAP];
    __shared__ unsigned short rs[N_NODES + 1];

    const int b    = blockIdx.x;
    const int tid  = threadIdx.x;
    const int slot = ind[b];

    const float* xb = inputs + (size_t)b * (2 * N_NODES * L_DIM);

    const float4* xb4 = (const float4*)xb;
    for (int k = tid; k < (N_NODES * L_DIM) / 4; k += 512) {
        const float4 v = xb4[k];
        const unsigned int lo = (f2bf_rtn_bits_hi(v.x) >> 16) | f2bf_rtn_bits_hi(v.y);
        const unsigned int hi = (f2bf_rtn_bits_hi(v.z) >> 16) | f2bf_rtn_bits_hi(v.w);
        ((uint2*)xsh)[k] = make_uint2(lo, hi);
    }
    const int EP = rs_p_g[N_NODES];
    const float* wrow = weight_diff + (size_t)slot * N_EDGES;
    for (int k = tid; k < EP; k += 512) {
        const unsigned int c = csr_p[k];
        wnb[k] = (c == 0xFFFFFFFFu) ? 0u
                                    : (f2bf_rtn_bits_hi(wrow[c >> 8]) | (c & 255u));
    }
    for (int n = tid; n <= N_NODES; n += 512) rs[n] = (unsigned short)rs_p_g[n];
    __syncthreads();

    const int lane = tid & 63;
    const int wv   = tid >> 6;
    float* ob = out + (size_t)b * (N_NODES * L_DIM);

    for (int n = wv; n < N_NODES; n += 8) {
        const int e0 = rs[n], e1 = rs[n + 1];
        float s = 0.f;
        #pragma unroll 4
        for (int k = e0; k < e1; ++k) {
            const unsigned int p = wnb[k];
            const float w  = __uint_as_float(p & 0xFFFF0000u);
            const float xv = __uint_as_float(
                (unsigned int)xsh[(p & 255u) * L_DIM + lane] << 16);
            s = fmaf(w, xv, s);
        }
        const float2 cb = coefbias[slot * N_NODES + n];
        const float  xg = xb[n * L_DIM + lane];
        ob[n * L_DIM + lane] = fmaf(cb.x, xg, cb.y) - s;
    }
}

extern "C" void kernel_launch(void* const* d_in, const int* in_sizes, int n_in,
                              void* d_out, int out_size, void* d_ws, size_t ws_size,
                              hipStream_t stream) {
    const float* inputs           = (const float*)d_in[0];
    const float* weight_diff      = (const float*)d_in[1];
    const float* bias_diffusion   = (const float*)d_in[2];
    const float* weight_self_loop = (const float*)d_in[3];
    const int*   ind              = (const int*)d_in[4];
    const int*   edge_i           = (const int*)d_in[5];
    const int*   edge_j           = (const int*)d_in[6];
    float* out = (float*)d_out;

    const int B = in_sizes[4];                 // 1024

    // ws layout (64B-aligned sections)
    char* ws = (char*)d_ws;
    int*          rs_p     = (int*)ws;                            //      1,024 B
    unsigned int* csr_p    = (unsigned int*)(ws + 1024);          //     16,384 B
    int*          stream_T = (int*)(ws + 17408);                  //         64 B
    unsigned int* m32      = (unsigned int*)(ws + 17472);         //     33,024 B
    float2*       coefbias = (float2*)(ws + 50496);               //    476,928 B
    unsigned int* p32      = (unsigned int*)(ws + 527424);        //  9,510,912 B
    const size_t WS_FULL = 527424 + (size_t)N_SLOTS * SLOT_U32 * sizeof(unsigned int);

    const bool full = (d_ws != nullptr) && (ws_size >= WS_FULL);

    build_csr_kernel<<<1, 256, 0, stream>>>(
        edge_i, edge_j, rs_p, csr_p, m32, stream_T);
    coef_eb_kernel<<<N_SLOTS, 256, 0, stream>>>(
        weight_diff, bias_diffusion, weight_self_loop, rs_p, csr_p, m32, stream_T,
        coefbias, full ? p32 : nullptr);
    if (full) {
        diffusion_stream_kernel<<<B, 512, 0, stream>>>(
            inputs, ind, stream_T, p32, coefbias, out);
    } else {
        diffusion_gcn_fallback<<<B, 512, 0, stream>>>(
            inputs, weight_diff, ind, rs_p, csr_p, coefbias, out);
    }
}